// Round 21
// baseline (198.915 us; speedup 1.0000x reference)
//
#include <hip/hip_runtime.h>
#include <hip/hip_bf16.h>

#define B_ 4
#define T_ 2048
#define C_ 1024
#define NH 16
#define HD 64
#define M_TOK (B_*T_)   // 8192

typedef unsigned short u16;
typedef __bf16 bf16x8 __attribute__((ext_vector_type(8)));
typedef short short8 __attribute__((ext_vector_type(8)));
typedef float f32x4 __attribute__((ext_vector_type(4)));
typedef unsigned u32x4 __attribute__((ext_vector_type(4)));
typedef unsigned short u16x4 __attribute__((ext_vector_type(4)));

static __device__ __forceinline__ u16 f2bf(float f) {
    union { float f; unsigned u; } a; a.f = f;
    unsigned u = a.u;
    u = u + 0x7fff + ((u >> 16) & 1);   // RNE
    return (u16)(u >> 16);
}

static __device__ __forceinline__ unsigned cvtpk(float lo, float hi) {
    unsigned r;
    asm("v_cvt_pk_bf16_f32 %0, %1, %2" : "=v"(r) : "v"(lo), "v"(hi));
    return r;
}

static __device__ __forceinline__ f32x4 mfma16(short8 a, short8 b, f32x4 c) {
    return __builtin_amdgcn_mfma_f32_16x16x32_bf16(
        __builtin_bit_cast(bf16x8, a), __builtin_bit_cast(bf16x8, b), c, 0, 0, 0);
}

// async global -> LDS, 16B per lane; lds base must be wave-uniform
#define GLOAD16(gp, lp) __builtin_amdgcn_global_load_lds( \
    (const __attribute__((address_space(1))) unsigned*)(const void*)(gp), \
    (__attribute__((address_space(3))) unsigned*)(void*)(lp), 16, 0, 0)

// ---------------- elementwise fp32 -> bf16 ----------------
__global__ void convert_x(const float* __restrict__ src, u16* __restrict__ dst, int n4) {
    int i = blockIdx.x * blockDim.x + threadIdx.x;
    if (i < n4) {
        const float4 v = *(const float4*)(src + (size_t)i * 4);
        u16x4 o;
        o[0] = f2bf(v.x); o[1] = f2bf(v.y); o[2] = f2bf(v.z); o[3] = f2bf(v.w);
        *(u16x4*)(dst + (size_t)i * 4) = o;
    }
}

// ---------------- transpose fp32 [rows][cols] -> bf16 [cols][rows] ----------------
__global__ void transpose_bf16(const float* __restrict__ src, u16* __restrict__ dst,
                               int rows, int cols) {
    __shared__ float tile[32][33];
    const int c0 = blockIdx.x * 32, r0 = blockIdx.y * 32;
    const int tx = threadIdx.x, ty = threadIdx.y;
    #pragma unroll
    for (int j = ty; j < 32; j += 8)
        tile[j][tx] = src[(size_t)(r0 + j) * cols + c0 + tx];
    __syncthreads();
    #pragma unroll
    for (int j = ty; j < 32; j += 8)
        dst[(size_t)(c0 + j) * rows + r0 + tx] = f2bf(tile[tx][j]);
}

// ---------------- bf16 GEMM v2: 128x128 tile, BK=64, swizzled LDS ----------------
template<int OUT_BF16>
__global__ __launch_bounds__(256) void gemm_bt(
    const u16* __restrict__ A,    // [M][K] bf16
    const u16* __restrict__ Bt,   // [N][K] bf16
    const float* __restrict__ bias, // [N]
    u16* __restrict__ Cb, float* __restrict__ Cf,
    int M, int N, int K, int scale_ncols, float scale)
{
    __shared__ u16 Al[128 * 64];
    __shared__ u16 Bl[128 * 64];
    const int tid  = threadIdx.x;
    const int lane = tid & 63;
    const int w    = tid >> 6;
    const int wr   = w >> 1, wc = w & 1;
    const int bm   = blockIdx.y * 128, bn = blockIdx.x * 128;

    f32x4 acc[4][4] = {};

    const int srow = tid >> 3;                         // 0..31
    const int schk = ((tid & 7) ^ (srow & 7)) * 8;     // pre-swizzled source chunk
    const u16* gA = A  + (size_t)(bm + srow) * K + schk;
    const u16* gB = Bt + (size_t)(bn + srow) * K + schk;
    u16* lA = &Al[(w << 3) * 64];                      // wave-uniform base (row w*8)
    u16* lB = &Bl[(w << 3) * 64];

    const int fr = lane & 15;
    const int fg = lane >> 4;

    for (int k0 = 0; k0 < K; k0 += 64) {
        #pragma unroll
        for (int inst = 0; inst < 4; inst++) {
            GLOAD16(gA + (size_t)(inst * 32) * K + k0, lA + inst * 32 * 64);
            GLOAD16(gB + (size_t)(inst * 32) * K + k0, lB + inst * 32 * 64);
        }
        __syncthreads();   // drains vmcnt -> LDS valid

        #pragma unroll
        for (int ks = 0; ks < 2; ks++) {
            short8 af[4], bfr[4];
            #pragma unroll
            for (int m = 0; m < 4; m++) {
                const int rh = wr * 64 + m * 16 + fr;
                af[m] = *(const short8*)&Al[rh * 64 + ((((ks << 2) | fg) ^ (fr & 7)) << 3)];
            }
            #pragma unroll
            for (int n = 0; n < 4; n++) {
                const int rh = wc * 64 + n * 16 + fr;
                bfr[n] = *(const short8*)&Bl[rh * 64 + ((((ks << 2) | fg) ^ (fr & 7)) << 3)];
            }
            #pragma unroll
            for (int m = 0; m < 4; m++)
                #pragma unroll
                for (int n = 0; n < 4; n++)
                    acc[m][n] = mfma16(af[m], bfr[n], acc[m][n]);
        }
        __syncthreads();
    }

    const int r0 = (lane >> 4) * 4;
    #pragma unroll
    for (int m = 0; m < 4; m++) {
        #pragma unroll
        for (int i = 0; i < 4; i++) {
            const int grow = bm + wr * 64 + m * 16 + r0 + i;
            #pragma unroll
            for (int n = 0; n < 4; n++) {
                const int gcol = bn + wc * 64 + n * 16 + fr;
                float v = acc[m][n][i] + bias[gcol];
                if (gcol < scale_ncols) v *= scale;
                if (OUT_BF16) Cb[(size_t)grow * N + gcol] = f2bf(v);
                else          Cf[(size_t)grow * N + gcol] = v;
            }
        }
    }
}

// ---------------- causal flash attention v13: K staged via global_load_lds ------
// K tile uses the proven GEMM-v2 template: linear Kl[64*64] holding chunk-swizzled
// content (pre-swizzled global source, chunk' = chunk ^ (row&7)); async GLOAD16
// issued right after the barrier into the non-compute buffer; the next iteration's
// barrier drains vmcnt before any read. V staging unchanged (R20-verbatim).
__global__ __launch_bounds__(256, 2) void attn_fwd(
    const u16* __restrict__ qkv,   // [M_TOK][3C] bf16 (Q pre-scaled by 0.125*log2e)
    u16* __restrict__ out)         // [M_TOK][C] bf16
{
    __shared__ u16 Kl[2][64 * 64]; // [buf][row*64 + swizzled-chunk*8]
    __shared__ u16 Vp[2][64 * 64]; // [buf][d][kv-slot], XOR-swizzled granules

    const int tid  = threadIdx.x;
    const int lane = tid & 63;
    const int wv   = tid >> 6;
    const int bid  = blockIdx.x;
    const int head = bid & 63;             // same XCD for all 16 blocks of a head
    const int b = head >> 4, h = head & 15;
    const int qt = bid >> 6;               // per-CU spread via +256 block striding
    const int tok0 = b * T_;
    const int q0 = qt * 128 + wv * 32;
    const int fr = lane & 15;
    const int fg = lane >> 4;
    const int fk = fg * 8;

    short8 aq[2][2];
    #pragma unroll
    for (int rg = 0; rg < 2; rg++) {
        const u16* qp = qkv + (size_t)(tok0 + q0 + rg * 16 + fr) * (3 * C_) + h * HD;
        aq[rg][0] = *(const short8*)(qp + fk);
        aq[rg][1] = *(const short8*)(qp + 32 + fk);
    }

    f32x4 oacc[2][4] = {};
    float mrow[2] = { -INFINITY, -INFINITY };
    float lsum[2] = { 0.f, 0.f };

    // K staging (GLOAD16): thread t covers row t>>3 (+32 for 2nd inst), slot t&7,
    // source chunk pre-swizzled by ^(row&7). Wave-uniform LDS base = row wv*8.
    const int ksrow = tid >> 3;                        // 0..31
    const int kschk = ((tid & 7) ^ (ksrow & 7)) * 8;   // pre-swizzled source chunk
    // V staging (conflict-free scatter): row lane, d-window wv*16
    const int kvrv  = lane;
    const int dbase = wv * 16;
    const int s_  = (kvrv & 32) | (((kvrv >> 2) & 3) << 3) | (((kvrv >> 4) & 1) << 2) | (kvrv & 3);
    const int vgcol = s_ >> 3;
    const int vso   = s_ & 7;

    short8 vreg0, vreg1;

#define KSTAGE(kt_, bf) { \
    const u16* kg = qkv + (size_t)(tok0 + (kt_) * 64 + ksrow) * (3 * C_) + C_ + h * HD + kschk; \
    GLOAD16(kg,                          &Kl[bf][(wv << 3) * 64]); \
    GLOAD16(kg + (size_t)32 * (3 * C_),  &Kl[bf][(32 + (wv << 3)) * 64]); }

#define LOAD_TILE(kt_) { \
    const u16* kpv = qkv + (size_t)(tok0 + (kt_) * 64 + kvrv) * (3 * C_) + 2 * C_ + h * HD + dbase; \
    vreg0 = *(const short8*)kpv;        vreg1 = *(const short8*)(kpv + 8); }

#define WRITE_TILE(bf) { \
    _Pragma("unroll") \
    for (int j = 0; j < 8; j++) { \
        Vp[bf][(dbase + j)     * 64 + (((vgcol ^ j) & 7) << 3) + vso] = (u16)vreg0[j]; \
        Vp[bf][(dbase + 8 + j) * 64 + (((vgcol ^ j) & 7) << 3) + vso] = (u16)vreg1[j]; } }

    KSTAGE(0, 0);                 // async K tile 0; drained by first barrier
    LOAD_TILE(0); WRITE_TILE(0);  // V tile 0

    const int ntiles = 2 * qt + 2;
    #pragma unroll 1
    for (int kt = 0; kt < ntiles; ++kt) {
        const int cb = kt & 1;
        const bool havenext = (kt + 1 < ntiles);
        if (havenext) LOAD_TILE(kt + 1);     // V regs (pre-barrier, as R20)
        __syncthreads();                     // drains vmcnt: Kl[cb] valid
        if (havenext) KSTAGE(kt + 1, !cb);   // async K into other buffer

        if (kt * 64 <= q0 + 31) {
            #pragma unroll
            for (int rg = 0; rg < 2; rg++) {
                f32x4 s[4] = {};
                __builtin_amdgcn_s_setprio(1);
                #pragma unroll
                for (int fc = 0; fc < 4; fc++) {
                    const int rb = (fc * 16 + fr) * 64;
                    const short8 k0 = *(const short8*)&Kl[cb][rb + ((fg ^ (fr & 7)) << 3)];
                    const short8 k1 = *(const short8*)&Kl[cb][rb + (((4 + fg) ^ (fr & 7)) << 3)];
                    s[fc] = mfma16(k0, aq[rg][0], s[fc]);
                    s[fc] = mfma16(k1, aq[rg][1], s[fc]);
                }
                __builtin_amdgcn_s_setprio(0);

                const int qg = q0 + rg * 16 + fr;
                if (kt * 64 + 63 > q0 + rg * 16) {     // diagonal tile: apply mask
                    #pragma unroll
                    for (int fc = 0; fc < 4; fc++)
                        #pragma unroll
                        for (int i = 0; i < 4; i++)
                            if (kt * 64 + fc * 16 + fg * 4 + i > qg) s[fc][i] = -INFINITY;
                }
                float pmax = -INFINITY;
                #pragma unroll
                for (int fc = 0; fc < 4; fc++)
                    #pragma unroll
                    for (int i = 0; i < 4; i++)
                        pmax = fmaxf(pmax, s[fc][i]);
                pmax = fmaxf(pmax, __shfl_xor(pmax, 16, 64));
                pmax = fmaxf(pmax, __shfl_xor(pmax, 32, 64));

                if (!__all(pmax <= mrow[rg] + 11.0f)) {
                    const float mnew = fmaxf(mrow[rg], pmax);
                    const float alpha = __builtin_amdgcn_exp2f(mrow[rg] - mnew);
                    mrow[rg] = mnew;
                    lsum[rg] *= alpha;
                    float av[4];
                    #pragma unroll
                    for (int i = 0; i < 4; i++) av[i] = __shfl(alpha, (fg << 2) + i, 64);
                    #pragma unroll
                    for (int df = 0; df < 4; df++)
                        #pragma unroll
                        for (int i = 0; i < 4; i++) oacc[rg][df][i] *= av[i];
                }
                const float mref = mrow[rg];

                float ps = 0.f;
                u32x4 wl[2];
                #pragma unroll
                for (int fc = 0; fc < 4; fc++) {
                    const float p0 = __builtin_amdgcn_exp2f(s[fc][0] - mref);
                    const float p1 = __builtin_amdgcn_exp2f(s[fc][1] - mref);
                    const float p2 = __builtin_amdgcn_exp2f(s[fc][2] - mref);
                    const float p3 = __builtin_amdgcn_exp2f(s[fc][3] - mref);
                    ps += (p0 + p1) + (p2 + p3);
                    wl[fc >> 1][(fc & 1) * 2 + 0] = cvtpk(p0, p1);
                    wl[fc >> 1][(fc & 1) * 2 + 1] = cvtpk(p2, p3);
                }
                ps += __shfl_xor(ps, 16, 64);
                ps += __shfl_xor(ps, 32, 64);
                lsum[rg] += ps;

                __builtin_amdgcn_s_setprio(1);
                #pragma unroll
                for (int c = 0; c < 2; c++) {
                    const short8 ap = __builtin_bit_cast(short8, wl[c]);
                    #pragma unroll
                    for (int df = 0; df < 4; df++) {
                        const short8 bv = *(const short8*)
                            &Vp[cb][(df * 16 + fr) * 64 + ((((c << 2) + fg) ^ (fr & 7)) << 3)];
                        oacc[rg][df] = mfma16(ap, bv, oacc[rg][df]);
                    }
                }
                __builtin_amdgcn_s_setprio(0);
            }
        }
        if (havenext) WRITE_TILE(!cb);
    }

    #pragma unroll
    for (int rg = 0; rg < 2; rg++) {
        #pragma unroll
        for (int i = 0; i < 4; i++) {
            const float li = __shfl(lsum[rg], (fg << 2) + i, 64);
            const float inv = 1.f / li;
            const int tokn = tok0 + q0 + rg * 16 + fg * 4 + i;
            #pragma unroll
            for (int df = 0; df < 4; df++)
                out[(size_t)tokn * C_ + h * HD + df * 16 + fr] = f2bf(oacc[rg][df][i] * inv);
        }
    }
#undef KSTAGE
#undef LOAD_TILE
#undef WRITE_TILE
}

extern "C" void kernel_launch(void* const* d_in, const int* in_sizes, int n_in,
                              void* d_out, int out_size, void* d_ws, size_t ws_size,
                              hipStream_t stream) {
    const float* hs    = (const float*)d_in[0];
    const float* w_qkv = (const float*)d_in[1];
    const float* b_qkv = (const float*)d_in[2];
    const float* w_o   = (const float*)d_in[3];
    const float* b_o   = (const float*)d_in[4];
    float* out = (float*)d_out;

    u16* Xb    = (u16*)d_ws;                            // [8192][1024]
    u16* WqkvT = Xb    + (size_t)M_TOK * C_;            // [3072][1024]
    u16* WoT   = WqkvT + (size_t)3 * C_ * C_;           // [1024][1024]
    u16* QKV   = WoT   + (size_t)C_ * C_;               // [8192][3072]
    u16* AO    = QKV   + (size_t)M_TOK * 3 * C_;        // [8192][1024]

    {
        const int n4 = M_TOK * C_ / 4;
        convert_x<<<(n4 + 255) / 256, 256, 0, stream>>>(hs, Xb, n4);
        dim3 tb(32, 8);
        transpose_bf16<<<dim3(3 * C_ / 32, C_ / 32), tb, 0, stream>>>(w_qkv, WqkvT, C_, 3 * C_);
        transpose_bf16<<<dim3(C_ / 32, C_ / 32), tb, 0, stream>>>(w_o, WoT, C_, C_);
    }

    // QKV projection; Q columns pre-scaled by 0.125*log2(e) (log2-domain softmax)
    gemm_bt<1><<<dim3(3 * C_ / 128, M_TOK / 128), 256, 0, stream>>>(
        Xb, WqkvT, b_qkv, QKV, nullptr, M_TOK, 3 * C_, C_, C_, 0.125f * 1.44269504f);

    attn_fwd<<<dim3(T_ / 128 * B_ * NH), 256, 0, stream>>>(QKV, AO);

    gemm_bt<0><<<dim3(C_ / 128, M_TOK / 128), 256, 0, stream>>>(
        AO, WoT, b_o, nullptr, out, M_TOK, C_, C_, 0, 1.f);
}

// Round 22
// 195.719 us; speedup vs baseline: 1.0163x; 1.0163x over previous
//
#include <hip/hip_runtime.h>
#include <hip/hip_bf16.h>

#define B_ 4
#define T_ 2048
#define C_ 1024
#define NH 16
#define HD 64
#define M_TOK (B_*T_)   // 8192

typedef unsigned short u16;
typedef __bf16 bf16x8 __attribute__((ext_vector_type(8)));
typedef short short8 __attribute__((ext_vector_type(8)));
typedef float f32x4 __attribute__((ext_vector_type(4)));
typedef unsigned u32x4 __attribute__((ext_vector_type(4)));
typedef unsigned short u16x4 __attribute__((ext_vector_type(4)));

static __device__ __forceinline__ u16 f2bf(float f) {
    union { float f; unsigned u; } a; a.f = f;
    unsigned u = a.u;
    u = u + 0x7fff + ((u >> 16) & 1);   // RNE
    return (u16)(u >> 16);
}

static __device__ __forceinline__ unsigned cvtpk(float lo, float hi) {
    unsigned r;
    asm("v_cvt_pk_bf16_f32 %0, %1, %2" : "=v"(r) : "v"(lo), "v"(hi));
    return r;
}

static __device__ __forceinline__ f32x4 mfma16(short8 a, short8 b, f32x4 c) {
    return __builtin_amdgcn_mfma_f32_16x16x32_bf16(
        __builtin_bit_cast(bf16x8, a), __builtin_bit_cast(bf16x8, b), c, 0, 0, 0);
}

// async global -> LDS, 16B per lane; lds base must be wave-uniform
#define GLOAD16(gp, lp) __builtin_amdgcn_global_load_lds( \
    (const __attribute__((address_space(1))) unsigned*)(const void*)(gp), \
    (__attribute__((address_space(3))) unsigned*)(void*)(lp), 16, 0, 0)

// ---------------- elementwise fp32 -> bf16 ----------------
__global__ void convert_x(const float* __restrict__ src, u16* __restrict__ dst, int n4) {
    int i = blockIdx.x * blockDim.x + threadIdx.x;
    if (i < n4) {
        const float4 v = *(const float4*)(src + (size_t)i * 4);
        u16x4 o;
        o[0] = f2bf(v.x); o[1] = f2bf(v.y); o[2] = f2bf(v.z); o[3] = f2bf(v.w);
        *(u16x4*)(dst + (size_t)i * 4) = o;
    }
}

// ---------------- transpose fp32 [rows][cols] -> bf16 [cols][rows] ----------------
__global__ void transpose_bf16(const float* __restrict__ src, u16* __restrict__ dst,
                               int rows, int cols) {
    __shared__ float tile[32][33];
    const int c0 = blockIdx.x * 32, r0 = blockIdx.y * 32;
    const int tx = threadIdx.x, ty = threadIdx.y;
    #pragma unroll
    for (int j = ty; j < 32; j += 8)
        tile[j][tx] = src[(size_t)(r0 + j) * cols + c0 + tx];
    __syncthreads();
    #pragma unroll
    for (int j = ty; j < 32; j += 8)
        dst[(size_t)(c0 + j) * rows + r0 + tx] = f2bf(tile[tx][j]);
}

// ---------------- bf16 GEMM v2: 128x128 tile, BK=64, swizzled LDS ----------------
// m97 2-barrier skeleton. global_load_lds into linear [128][64] LDS whose content
// is chunk-swizzled via pre-swizzled global source (chunk' = chunk ^ (row&7));
// ds_read side applies the same involution -> conflict-free b128 fragment reads.
template<int OUT_BF16>
__global__ __launch_bounds__(256) void gemm_bt(
    const u16* __restrict__ A,    // [M][K] bf16
    const u16* __restrict__ Bt,   // [N][K] bf16
    const float* __restrict__ bias, // [N]
    u16* __restrict__ Cb, float* __restrict__ Cf,
    int M, int N, int K, int scale_ncols, float scale)
{
    __shared__ u16 Al[128 * 64];
    __shared__ u16 Bl[128 * 64];
    const int tid  = threadIdx.x;
    const int lane = tid & 63;
    const int w    = tid >> 6;
    const int wr   = w >> 1, wc = w & 1;
    const int bm   = blockIdx.y * 128, bn = blockIdx.x * 128;

    f32x4 acc[4][4] = {};

    const int srow = tid >> 3;                         // 0..31
    const int schk = ((tid & 7) ^ (srow & 7)) * 8;     // pre-swizzled source chunk
    const u16* gA = A  + (size_t)(bm + srow) * K + schk;
    const u16* gB = Bt + (size_t)(bn + srow) * K + schk;
    u16* lA = &Al[(w << 3) * 64];                      // wave-uniform base (row w*8)
    u16* lB = &Bl[(w << 3) * 64];

    const int fr = lane & 15;
    const int fg = lane >> 4;

    for (int k0 = 0; k0 < K; k0 += 64) {
        #pragma unroll
        for (int inst = 0; inst < 4; inst++) {
            GLOAD16(gA + (size_t)(inst * 32) * K + k0, lA + inst * 32 * 64);
            GLOAD16(gB + (size_t)(inst * 32) * K + k0, lB + inst * 32 * 64);
        }
        __syncthreads();   // drains vmcnt -> LDS valid

        #pragma unroll
        for (int ks = 0; ks < 2; ks++) {
            short8 af[4], bfr[4];
            #pragma unroll
            for (int m = 0; m < 4; m++) {
                const int rh = wr * 64 + m * 16 + fr;
                af[m] = *(const short8*)&Al[rh * 64 + ((((ks << 2) | fg) ^ (fr & 7)) << 3)];
            }
            #pragma unroll
            for (int n = 0; n < 4; n++) {
                const int rh = wc * 64 + n * 16 + fr;
                bfr[n] = *(const short8*)&Bl[rh * 64 + ((((ks << 2) | fg) ^ (fr & 7)) << 3)];
            }
            #pragma unroll
            for (int m = 0; m < 4; m++)
                #pragma unroll
                for (int n = 0; n < 4; n++)
                    acc[m][n] = mfma16(af[m], bfr[n], acc[m][n]);
        }
        __syncthreads();
    }

    const int r0 = (lane >> 4) * 4;
    #pragma unroll
    for (int m = 0; m < 4; m++) {
        #pragma unroll
        for (int i = 0; i < 4; i++) {
            const int grow = bm + wr * 64 + m * 16 + r0 + i;
            #pragma unroll
            for (int n = 0; n < 4; n++) {
                const int gcol = bn + wc * 64 + n * 16 + fr;
                float v = acc[m][n][i] + bias[gcol];
                if (gcol < scale_ncols) v *= scale;
                if (OUT_BF16) Cb[(size_t)grow * N + gcol] = f2bf(v);
                else          Cf[(size_t)grow * N + gcol] = v;
            }
        }
    }
}

// ---------------- causal flash attention (R20 verbatim — best proven state) -----
__global__ __launch_bounds__(256, 2) void attn_fwd(
    const u16* __restrict__ qkv,   // [M_TOK][3C] bf16 (Q pre-scaled by 0.125*log2e)
    u16* __restrict__ out)         // [M_TOK][C] bf16
{
    __shared__ u16 Kl[2][64][72];  // [buf][kv][d], +8 pad
    __shared__ u16 Vp[2][64 * 64]; // [buf][d][kv-slot], XOR-swizzled granules

    const int tid  = threadIdx.x;
    const int lane = tid & 63;
    const int wv   = tid >> 6;
    const int bid  = blockIdx.x;
    const int head = bid & 63;             // same XCD for all 16 blocks of a head
    const int b = head >> 4, h = head & 15;
    const int qt = bid >> 6;               // per-CU spread via +256 block striding
    const int tok0 = b * T_;
    const int q0 = qt * 128 + wv * 32;
    const int fr = lane & 15;
    const int fg = lane >> 4;
    const int fk = fg * 8;

    short8 aq[2][2];
    #pragma unroll
    for (int rg = 0; rg < 2; rg++) {
        const u16* qp = qkv + (size_t)(tok0 + q0 + rg * 16 + fr) * (3 * C_) + h * HD;
        aq[rg][0] = *(const short8*)(qp + fk);
        aq[rg][1] = *(const short8*)(qp + 32 + fk);
    }

    f32x4 oacc[2][4] = {};
    float mrow[2] = { -INFINITY, -INFINITY };
    float lsum[2] = { 0.f, 0.f };

    const int kvrk = tid >> 2;
    const int kck  = (tid & 3) * 8;
    const int kvrv  = lane;
    const int dbase = wv * 16;
    const int s_  = (kvrv & 32) | (((kvrv >> 2) & 3) << 3) | (((kvrv >> 4) & 1) << 2) | (kvrv & 3);
    const int vgcol = s_ >> 3;
    const int vso   = s_ & 7;

    short8 kreg0, kreg1, vreg0, vreg1;

#define LOAD_TILE(kt_) { \
    const u16* kpk = qkv + (size_t)(tok0 + (kt_) * 64 + kvrk) * (3 * C_) + C_ + h * HD + kck; \
    kreg0 = *(const short8*)kpk;        kreg1 = *(const short8*)(kpk + 32); \
    const u16* kpv = qkv + (size_t)(tok0 + (kt_) * 64 + kvrv) * (3 * C_) + 2 * C_ + h * HD + dbase; \
    vreg0 = *(const short8*)kpv;        vreg1 = *(const short8*)(kpv + 8); }

#define WRITE_TILE(bf) { \
    *(short8*)&Kl[bf][kvrk][kck]      = kreg0; \
    *(short8*)&Kl[bf][kvrk][kck + 32] = kreg1; \
    _Pragma("unroll") \
    for (int j = 0; j < 8; j++) { \
        Vp[bf][(dbase + j)     * 64 + (((vgcol ^ j) & 7) << 3) + vso] = (u16)vreg0[j]; \
        Vp[bf][(dbase + 8 + j) * 64 + (((vgcol ^ j) & 7) << 3) + vso] = (u16)vreg1[j]; } }

    LOAD_TILE(0); WRITE_TILE(0);

    const int ntiles = 2 * qt + 2;
    #pragma unroll 1
    for (int kt = 0; kt < ntiles; ++kt) {
        const int cb = kt & 1;
        const bool havenext = (kt + 1 < ntiles);
        if (havenext) LOAD_TILE(kt + 1);
        __syncthreads();

        if (kt * 64 <= q0 + 31) {
            #pragma unroll
            for (int rg = 0; rg < 2; rg++) {
                f32x4 s[4] = {};
                __builtin_amdgcn_s_setprio(1);
                #pragma unroll
                for (int fc = 0; fc < 4; fc++) {
                    const short8 k0 = *(const short8*)&Kl[cb][fc * 16 + fr][fk];
                    const short8 k1 = *(const short8*)&Kl[cb][fc * 16 + fr][32 + fk];
                    s[fc] = mfma16(k0, aq[rg][0], s[fc]);
                    s[fc] = mfma16(k1, aq[rg][1], s[fc]);
                }
                __builtin_amdgcn_s_setprio(0);

                const int qg = q0 + rg * 16 + fr;
                if (kt * 64 + 63 > q0 + rg * 16) {     // diagonal tile: apply mask
                    #pragma unroll
                    for (int fc = 0; fc < 4; fc++)
                        #pragma unroll
                        for (int i = 0; i < 4; i++)
                            if (kt * 64 + fc * 16 + fg * 4 + i > qg) s[fc][i] = -INFINITY;
                }
                float pmax = -INFINITY;
                #pragma unroll
                for (int fc = 0; fc < 4; fc++)
                    #pragma unroll
                    for (int i = 0; i < 4; i++)
                        pmax = fmaxf(pmax, s[fc][i]);
                pmax = fmaxf(pmax, __shfl_xor(pmax, 16, 64));
                pmax = fmaxf(pmax, __shfl_xor(pmax, 32, 64));

                if (!__all(pmax <= mrow[rg] + 11.0f)) {
                    const float mnew = fmaxf(mrow[rg], pmax);
                    const float alpha = __builtin_amdgcn_exp2f(mrow[rg] - mnew);
                    mrow[rg] = mnew;
                    lsum[rg] *= alpha;
                    float av[4];
                    #pragma unroll
                    for (int i = 0; i < 4; i++) av[i] = __shfl(alpha, (fg << 2) + i, 64);
                    #pragma unroll
                    for (int df = 0; df < 4; df++)
                        #pragma unroll
                        for (int i = 0; i < 4; i++) oacc[rg][df][i] *= av[i];
                }
                const float mref = mrow[rg];

                float ps = 0.f;
                u32x4 wl[2];
                #pragma unroll
                for (int fc = 0; fc < 4; fc++) {
                    const float p0 = __builtin_amdgcn_exp2f(s[fc][0] - mref);
                    const float p1 = __builtin_amdgcn_exp2f(s[fc][1] - mref);
                    const float p2 = __builtin_amdgcn_exp2f(s[fc][2] - mref);
                    const float p3 = __builtin_amdgcn_exp2f(s[fc][3] - mref);
                    ps += (p0 + p1) + (p2 + p3);
                    wl[fc >> 1][(fc & 1) * 2 + 0] = cvtpk(p0, p1);
                    wl[fc >> 1][(fc & 1) * 2 + 1] = cvtpk(p2, p3);
                }
                ps += __shfl_xor(ps, 16, 64);
                ps += __shfl_xor(ps, 32, 64);
                lsum[rg] += ps;

                __builtin_amdgcn_s_setprio(1);
                #pragma unroll
                for (int c = 0; c < 2; c++) {
                    const short8 ap = __builtin_bit_cast(short8, wl[c]);
                    #pragma unroll
                    for (int df = 0; df < 4; df++) {
                        const short8 bv = *(const short8*)
                            &Vp[cb][(df * 16 + fr) * 64 + ((((c << 2) + fg) ^ (fr & 7)) << 3)];
                        oacc[rg][df] = mfma16(ap, bv, oacc[rg][df]);
                    }
                }
                __builtin_amdgcn_s_setprio(0);
            }
        }
        if (havenext) WRITE_TILE(!cb);
    }

    #pragma unroll
    for (int rg = 0; rg < 2; rg++) {
        #pragma unroll
        for (int i = 0; i < 4; i++) {
            const float li = __shfl(lsum[rg], (fg << 2) + i, 64);
            const float inv = 1.f / li;
            const int tokn = tok0 + q0 + rg * 16 + fg * 4 + i;
            #pragma unroll
            for (int df = 0; df < 4; df++)
                out[(size_t)tokn * C_ + h * HD + df * 16 + fr] = f2bf(oacc[rg][df][i] * inv);
        }
    }
#undef LOAD_TILE
#undef WRITE_TILE
}

extern "C" void kernel_launch(void* const* d_in, const int* in_sizes, int n_in,
                              void* d_out, int out_size, void* d_ws, size_t ws_size,
                              hipStream_t stream) {
    const float* hs    = (const float*)d_in[0];
    const float* w_qkv = (const float*)d_in[1];
    const float* b_qkv = (const float*)d_in[2];
    const float* w_o   = (const float*)d_in[3];
    const float* b_o   = (const float*)d_in[4];
    float* out = (float*)d_out;

    u16* Xb    = (u16*)d_ws;                            // [8192][1024]
    u16* WqkvT = Xb    + (size_t)M_TOK * C_;            // [3072][1024]
    u16* WoT   = WqkvT + (size_t)3 * C_ * C_;           // [1024][1024]
    u16* QKV   = WoT   + (size_t)C_ * C_;               // [8192][3072]
    u16* AO    = QKV   + (size_t)M_TOK * 3 * C_;        // [8192][1024]

    {
        const int n4 = M_TOK * C_ / 4;
        convert_x<<<(n4 + 255) / 256, 256, 0, stream>>>(hs, Xb, n4);
        dim3 tb(32, 8);
        transpose_bf16<<<dim3(3 * C_ / 32, C_ / 32), tb, 0, stream>>>(w_qkv, WqkvT, C_, 3 * C_);
        transpose_bf16<<<dim3(C_ / 32, C_ / 32), tb, 0, stream>>>(w_o, WoT, C_, C_);
    }

    // QKV projection; Q columns pre-scaled by 0.125*log2(e) (log2-domain softmax)
    gemm_bt<1><<<dim3(3 * C_ / 128, M_TOK / 128), 256, 0, stream>>>(
        Xb, WqkvT, b_qkv, QKV, nullptr, M_TOK, 3 * C_, C_, C_, 0.125f * 1.44269504f);

    attn_fwd<<<dim3(T_ / 128 * B_ * NH), 256, 0, stream>>>(QKV, AO);

    gemm_bt<0><<<dim3(C_ / 128, M_TOK / 128), 256, 0, stream>>>(
        AO, WoT, b_o, nullptr, out, M_TOK, C_, C_, 0, 1.f);
}